// Round 7
// baseline (1070.107 us; speedup 1.0000x reference)
//
#include <hip/hip_runtime.h>
#include <stdint.h>

// LSTM_49357764165950 — MI355X (gfx950), round 7
// = R4-passing kernel EXACTLY (256 blocks = 32 tiles x 8 chunks, 256 thr, wf[4][12],
//   tagged-word exchange in d_out, XCD runtime check, full-gather tag-retry, 2-slot chain)
// + ONLY two protocol-neutral grafts:
//   (1) LDS strides ROWB=80/FRAGB=2608 (R4's 64B stride = 8-way bank conflict, 2.9e7 meas.)
//   (2) probe-first spin: poll ONE 4B tag word (src[0]) until tag==t+1, then run the
//       VERBATIM R4 full tagged gather retry. Same tags, same threads, no divergence
//       change, no ordering assumptions, no producer-side LDS writes, no done words.
//
// Slot-reuse safety (2 slots, R4 chain): a block overwrites slot s with tag t+2 only
// after its gather of t+1 succeeded => all partners published t+1 => all partners
// passed their end-of-iter-(t-1) barrier => their slot-s reads (tag t) are complete.

typedef float  f32x4  __attribute__((ext_vector_type(4)));
typedef float  f32x2  __attribute__((ext_vector_type(2)));
typedef short  bf16x8 __attribute__((ext_vector_type(8)));
typedef unsigned int u32x4 __attribute__((ext_vector_type(4)));

#define SMEM_SZ 86016      // force 1 block/CU (co-residency for spin protocol)
#define T_STEPS 255
#define ROWB    80         // bytes per 32-col bf16 row (64B data + 16B pad)
#define FRAGB   2608       // 32*80 + 48B pad
#define XT(b)   ((b)*4*FRAGB)               // x frags kf 0..3   (0, 10432)
#define HT(b)   (8*FRAGB + (b)*8*FRAGB)     // h frags 0..7      (20864, 41728; end 62592)
#define WM_OFF  62592                       // wm0[128] wm1[128] bem[128] f32 (+xs scratch)
#define H1_OFF  64128
#define C1_OFF  65152

#define AG_ST(p, v) __hip_atomic_store((p), (v), __ATOMIC_RELAXED, __HIP_MEMORY_SCOPE_AGENT)
#define AG_LD(p)    __hip_atomic_load((p),        __ATOMIC_RELAXED, __HIP_MEMORY_SCOPE_AGENT)

__device__ __forceinline__ unsigned short f2bf(float f){
  union { float f; unsigned int u; } v; v.f = f;
  unsigned int u = v.u;
  return (unsigned short)((u + 0x7fffu + ((u >> 16) & 1u)) >> 16);   // RTNE
}
__device__ __forceinline__ float sigf(float x){
  float e = __builtin_amdgcn_exp2f(-1.4426950408889634f * x);
  return __builtin_amdgcn_rcpf(1.0f + e);
}
__device__ __forceinline__ float tanh_(float x){
  float e = __builtin_amdgcn_exp2f(-2.8853900817779268f * x);
  return (1.0f - e) * __builtin_amdgcn_rcpf(1.0f + e);
}

__global__ void zero_ws(unsigned int* flags, unsigned int* outw){
  const unsigned idx = blockIdx.x*512u + threadIdx.x;
  if (idx < 16384u)        AG_ST(flags + idx, 0u);
  else if (idx < 540672u)  AG_ST(outw + (idx - 16384u), 0u);
}

__global__ void __launch_bounds__(256, 1)
lstm_k(const float* __restrict__ obs,
       const float* __restrict__ Wemb, const float* __restrict__ Bemb,
       const float* __restrict__ Wih,  const float* __restrict__ Whh,
       const float* __restrict__ bih,  const float* __restrict__ bhh,
       float* out, unsigned int* flags, unsigned int* hbuf)   // hbuf aliases out
{
  __shared__ __align__(16) char smem[SMEM_SZ];
  const int tid = threadIdx.x;
  const int l   = tid & 63;
  const int w   = tid >> 6;
  const int m   = w & 1;
  const int hf  = w >> 1;
  const int lc  = l & 15;
  const int lg  = l >> 4;
  const int chunk = blockIdx.x >> 5;
  const int tile  = blockIdx.x & 31;     // partners {tile+32k} share blockIdx%8

  // ---- XCD-affinity check, 2 rounds (decision provably tile-uniform) [R4 exact] ----
  unsigned xcc;
  asm volatile("s_getreg_b32 %0, hwreg(HW_REG_XCC_ID)" : "=s"(xcc));
  bool fast;
  {
    volatile unsigned* xs = (volatile unsigned*)(smem + WM_OFF);
    if (tid == 0) AG_ST(flags + (tile*8 + chunk)*16 + 8, 1u + xcc);
    if (tid < 8){
      unsigned v; long g = 0;
      do { v = AG_LD(flags + (tile*8 + tid)*16 + 8); } while (v == 0 && ++g < 10000000L);
      xs[tid] = v;
    }
    __syncthreads();
    unsigned ok = 1;
    #pragma unroll
    for (int j = 0; j < 8; ++j) ok &= (xs[j] == 1u + xcc) ? 1u : 0u;
    __syncthreads();
    if (tid == 0) AG_ST(flags + (tile*8 + chunk)*16 + 9, ok ? 2u : 1u);
    if (tid < 8){
      unsigned v; long g = 0;
      do { v = AG_LD(flags + (tile*8 + tid)*16 + 9); } while (v == 0 && ++g < 10000000L);
      xs[tid] = v;
    }
    __syncthreads();
    unsigned all2 = 1;
    #pragma unroll
    for (int j = 0; j < 8; ++j) all2 &= (xs[j] == 2u) ? 1u : 0u;
    fast = (all2 != 0);
    __syncthreads();
  }

  // ---- register-resident W fragments [R4 exact] ----
  bf16x8 wf[4][12];
  #pragma unroll
  for (int ni = 0; ni < 4; ++ni){
    const int rowg = ni*256 + chunk*32 + hf*16 + lc;
    #pragma unroll
    for (int kf = 0; kf < 12; ++kf){
      const int k0 = kf*32 + lg*8;
      const float* src = (k0 < 128) ? (Wih + rowg*128 + k0)
                                    : (Whh + rowg*256 + (k0 - 128));
      f32x4 s0 = *(const f32x4*)(src);
      f32x4 s1 = *(const f32x4*)(src + 4);
      bf16x8 v;
      v[0]=(short)f2bf(s0[0]); v[1]=(short)f2bf(s0[1]);
      v[2]=(short)f2bf(s0[2]); v[3]=(short)f2bf(s0[3]);
      v[4]=(short)f2bf(s1[0]); v[5]=(short)f2bf(s1[1]);
      v[6]=(short)f2bf(s1[2]); v[7]=(short)f2bf(s1[3]);
      wf[ni][kf] = v;
    }
  }
  float bias[4];
  #pragma unroll
  for (int ni = 0; ni < 4; ++ni){
    const int rowg = ni*256 + chunk*32 + hf*16 + lc;
    bias[ni] = bih[rowg] + bhh[rowg];
  }

  // ---- LDS tables + tag step [R4 exact] ----
  float* wm0 = (float*)(smem + WM_OFF);
  float* wm1 = wm0 + 128;
  float* bem = wm0 + 256;
  if (tid < 128){
    float a = 0.f, b = 0.f, c = 0.f;
    if (tid < 126){ a = 4.0f*Wemb[tid]; b = 4.0f*Wemb[126 + tid]; c = Bemb[tid]; }
    wm0[tid] = a; wm1[tid] = b; bem[tid] = c;
  }
  float* h1f = (float*)(smem + H1_OFF);
  float* c1f = (float*)(smem + C1_OFF);
  {
    const int j = tid;
    float gi  = Wih[(j      )*128 + 126] + bih[j      ] + bhh[j      ];
    float gg2 = Wih[(512 + j)*128 + 126] + bih[512 + j] + bhh[512 + j];
    float go  = Wih[(768 + j)*128 + 126] + bih[768 + j] + bhh[768 + j];
    float c1 = sigf(gi)*tanh_(gg2);
    h1f[j] = sigf(go)*tanh_(c1); c1f[j] = c1;
  }
  __syncthreads();

  // x-tile builder [R4 mapping, new strides]
  auto xtile = [&](int buf, float vx, float vy){
    const int row = tid >> 3;
    const int kf  = (tid & 7) >> 1;
    const int lgb = (tid & 1) * 2;
    const int c0  = kf*32 + lgb*8;
    f32x4 wa = *(const f32x4*)(wm0 + c0), wb = *(const f32x4*)(wm0 + c0 + 4);
    f32x4 wc = *(const f32x4*)(wm1 + c0), wd = *(const f32x4*)(wm1 + c0 + 4);
    f32x4 ba = *(const f32x4*)(bem + c0), bb = *(const f32x4*)(bem + c0 + 4);
    f32x4 we = *(const f32x4*)(wm0 + c0 + 8), wg = *(const f32x4*)(wm0 + c0 + 12);
    f32x4 wh = *(const f32x4*)(wm1 + c0 + 8), wi = *(const f32x4*)(wm1 + c0 + 12);
    f32x4 bc = *(const f32x4*)(bem + c0 + 8), bd = *(const f32x4*)(bem + c0 + 12);
    bf16x8 v0, v1;
    #pragma unroll
    for (int i = 0; i < 4; ++i){
      v0[i]     = (short)f2bf(fmaxf(vx*wa[i] + vy*wc[i] + ba[i], 0.f));
      v0[4 + i] = (short)f2bf(fmaxf(vx*wb[i] + vy*wd[i] + bb[i], 0.f));
      v1[i]     = (short)f2bf(fmaxf(vx*we[i] + vy*wh[i] + bc[i], 0.f));
      v1[4 + i] = (short)f2bf(fmaxf(vx*wg[i] + vy*wi[i] + bd[i], 0.f));
    }
    char* p = smem + XT(buf) + kf*FRAGB + row*ROWB + lgb*16;
    *(bf16x8*)(p)      = v0;
    *(bf16x8*)(p + 16) = v1;
  };

  // gather mapping [R4 exact]: thread owns (row gr, frag gg) = 32 cols
  const int gr = tid >> 3;
  const int gg = tid & 7;

  // c-state + h_tile[0] + x_tile[0]
  const int col = chunk*32 + hf*16 + lc;
  float cs[4];
  { float cv = c1f[col]; cs[0]=cv; cs[1]=cv; cs[2]=cv; cs[3]=cv; }
  {
    const int hc0 = gg*32;
    bf16x8 v0, v1, v2, v3;
    #pragma unroll
    for (int i = 0; i < 8; ++i){
      v0[i] = (short)f2bf(h1f[hc0 + i]);      v1[i] = (short)f2bf(h1f[hc0 + 8 + i]);
      v2[i] = (short)f2bf(h1f[hc0 + 16 + i]); v3[i] = (short)f2bf(h1f[hc0 + 24 + i]);
    }
    char* pb = smem + HT(0) + gg*FRAGB + gr*ROWB;
    *(bf16x8*)(pb) = v0; *(bf16x8*)(pb+16) = v1; *(bf16x8*)(pb+32) = v2; *(bf16x8*)(pb+48) = v3;
  }
  {
    const float* op = obs + (tile*32 + gr)*512;
    f32x2 p0 = *(const f32x2*)(op), p1 = *(const f32x2*)(op + 2);
    xtile(0, p1[0] - p0[0], p1[1] - p0[1]);
  }
  __syncthreads();

  float hv[4] = {0.f, 0.f, 0.f, 0.f};
  long guard = 0;
  const int prow = m*16 + lg*4;

  for (int t = 0; t < T_STEPS; ++t){
    const int cur = t & 1;
    float vx = 0.f, vy = 0.f;
    if (t < T_STEPS - 1){
      const float* op = obs + (tile*32 + gr)*512 + (t + 1)*2;
      f32x2 p0 = *(const f32x2*)(op), p1 = *(const f32x2*)(op + 2);
      vx = p1[0] - p0[0]; vy = p1[1] - p0[1];
    }
    // ---- MFMA [R4 exact, new strides] ----
    f32x4 acc0 = (f32x4){bias[0],bias[0],bias[0],bias[0]};
    f32x4 acc1 = (f32x4){bias[1],bias[1],bias[1],bias[1]};
    f32x4 acc2 = (f32x4){bias[2],bias[2],bias[2],bias[2]};
    f32x4 acc3 = (f32x4){bias[3],bias[3],bias[3],bias[3]};
    {
      const int rowA = m*16 + lc;
      #pragma unroll
      for (int kf = 0; kf < 12; ++kf){
        const char* pa = smem + ((kf < 4) ? (XT(cur) + kf*FRAGB)
                                          : (HT(cur) + (kf - 4)*FRAGB))
                              + rowA*ROWB + lg*16;
        bf16x8 a = *(const bf16x8*)pa;
        acc0 = __builtin_amdgcn_mfma_f32_16x16x32_bf16(a, wf[0][kf], acc0, 0, 0, 0);
        acc1 = __builtin_amdgcn_mfma_f32_16x16x32_bf16(a, wf[1][kf], acc1, 0, 0, 0);
        acc2 = __builtin_amdgcn_mfma_f32_16x16x32_bf16(a, wf[2][kf], acc2, 0, 0, 0);
        acc3 = __builtin_amdgcn_mfma_f32_16x16x32_bf16(a, wf[3][kf], acc3, 0, 0, 0);
      }
    }
    // ---- elementwise [R4 exact] ----
    #pragma unroll
    for (int r = 0; r < 4; ++r){
      cs[r] = sigf(acc1[r])*cs[r] + sigf(acc0[r])*tanh_(acc2[r]);
      hv[r] = sigf(acc3[r])*tanh_(cs[r]);
    }

    if (t < T_STEPS - 1){
      const int slot = (t + 1) & 1;
      const unsigned want = ((unsigned)(t + 1)) << 16;

      // ---- publish own chunk (tagged) [R4 exact] ----
      {
        unsigned w0 = want | f2bf(hv[0]);
        unsigned w1 = want | f2bf(hv[1]);
        unsigned w2 = want | f2bf(hv[2]);
        unsigned w3 = want | f2bf(hv[3]);
        unsigned int* dst = hbuf + slot*262144 + tile*8192 + prow*256 + col;
        if (fast){
          asm volatile("global_store_dword %0, %1, off sc0\n\t"
                       "global_store_dword %0, %2, off offset:1024 sc0\n\t"
                       "global_store_dword %0, %3, off offset:2048 sc0\n\t"
                       "global_store_dword %0, %4, off offset:3072 sc0"
                       :: "v"(dst), "v"(w0), "v"(w1), "v"(w2), "v"(w3) : "memory");
        } else {
          AG_ST(dst, w0); AG_ST(dst + 256, w1); AG_ST(dst + 512, w2); AG_ST(dst + 768, w3);
        }
      }

      xtile(slot, vx, vy);               // overlaps partners' publish flight [R4 exact]

      // ---- NEW: probe-first spin on ONE 4B tag word (hint only; 32x less traffic) ----
      const unsigned int* src = hbuf + slot*262144 + tile*8192 + gr*256 + gg*32;
      {
        unsigned pv;
        do {
          if (fast){
            asm volatile("global_load_dword %0, %1, off sc0 nt\n\t"
                         "s_waitcnt vmcnt(0)"
                         : "=&v"(pv) : "v"(src) : "memory");
          } else {
            pv = AG_LD(src);
          }
          if (((pv ^ want) & 0xffff0000u) == 0) break;
          __builtin_amdgcn_s_sleep(1);
        } while (++guard < 2000000L);
      }

      // ---- full tagged gather with retry [R4 VERBATIM] ----
      {
        u32x4 q0, q1, q2, q3, q4, q5, q6, q7;
        unsigned bad;
        do {
          if (fast){
            asm volatile(
              "global_load_dwordx4 %0, %8, off sc0 nt\n\t"
              "global_load_dwordx4 %1, %8, off offset:16 sc0 nt\n\t"
              "global_load_dwordx4 %2, %8, off offset:32 sc0 nt\n\t"
              "global_load_dwordx4 %3, %8, off offset:48 sc0 nt\n\t"
              "global_load_dwordx4 %4, %8, off offset:64 sc0 nt\n\t"
              "global_load_dwordx4 %5, %8, off offset:80 sc0 nt\n\t"
              "global_load_dwordx4 %6, %8, off offset:96 sc0 nt\n\t"
              "global_load_dwordx4 %7, %8, off offset:112 sc0 nt\n\t"
              "s_waitcnt vmcnt(0)"
              : "=&v"(q0), "=&v"(q1), "=&v"(q2), "=&v"(q3),
                "=&v"(q4), "=&v"(q5), "=&v"(q6), "=&v"(q7)
              : "v"(src) : "memory");
          } else {
            #pragma unroll
            for (int i = 0; i < 4; ++i){
              q0[i] = AG_LD(src +      i); q1[i] = AG_LD(src +  4 + i);
              q2[i] = AG_LD(src +  8 + i); q3[i] = AG_LD(src + 12 + i);
              q4[i] = AG_LD(src + 16 + i); q5[i] = AG_LD(src + 20 + i);
              q6[i] = AG_LD(src + 24 + i); q7[i] = AG_LD(src + 28 + i);
            }
          }
          bad = 0;
          #pragma unroll
          for (int i = 0; i < 4; ++i){
            bad |= (q0[i] ^ want) & 0xffff0000u; bad |= (q1[i] ^ want) & 0xffff0000u;
            bad |= (q2[i] ^ want) & 0xffff0000u; bad |= (q3[i] ^ want) & 0xffff0000u;
            bad |= (q4[i] ^ want) & 0xffff0000u; bad |= (q5[i] ^ want) & 0xffff0000u;
            bad |= (q6[i] ^ want) & 0xffff0000u; bad |= (q7[i] ^ want) & 0xffff0000u;
          }
        } while (bad && ++guard < 2000000L);

        bf16x8 v0, v1, v2, v3;
        #pragma unroll
        for (int i = 0; i < 4; ++i){
          v0[i] = (short)(q0[i] & 0xffffu); v0[4+i] = (short)(q1[i] & 0xffffu);
          v1[i] = (short)(q2[i] & 0xffffu); v1[4+i] = (short)(q3[i] & 0xffffu);
          v2[i] = (short)(q4[i] & 0xffffu); v2[4+i] = (short)(q5[i] & 0xffffu);
          v3[i] = (short)(q6[i] & 0xffffu); v3[4+i] = (short)(q7[i] & 0xffffu);
        }
        char* pb = smem + HT(slot) + gg*FRAGB + gr*ROWB;
        *(bf16x8*)(pb) = v0; *(bf16x8*)(pb+16) = v1; *(bf16x8*)(pb+32) = v2; *(bf16x8*)(pb+48) = v3;
      }
    }
    __syncthreads();
  }

  // ---- done-rendezvous before epilogue overwrites hbuf slot0 [R4 exact] ----
  if (tid == 0) AG_ST(flags + (tile*8 + chunk)*16 + 10, 1u);
  if (tid < 8){
    unsigned v; long g = 0;
    do { v = AG_LD(flags + (tile*8 + tid)*16 + 10); } while (v == 0 && ++g < 10000000L);
  }
  __syncthreads();

  // ---- epilogue [R4 exact] ----
  {
    const int row0 = tile*32 + prow;
    #pragma unroll
    for (int r = 0; r < 4; ++r){
      out[(row0 + r)*256 + col]          = hv[r];
      out[262144 + (row0 + r)*256 + col] = cs[r];
    }
  }
}

extern "C" void kernel_launch(void* const* d_in, const int* in_sizes, int n_in,
                              void* d_out, int out_size, void* d_ws, size_t ws_size,
                              hipStream_t stream) {
  (void)in_sizes; (void)n_in; (void)out_size; (void)ws_size;
  const float* obs  = (const float*)d_in[0];
  /* d_in[1] = pooled: unused */
  const float* Wemb = (const float*)d_in[2];
  const float* Bemb = (const float*)d_in[3];
  const float* Wih  = (const float*)d_in[4];
  const float* Whh  = (const float*)d_in[5];
  const float* bih  = (const float*)d_in[6];
  const float* bhh  = (const float*)d_in[7];
  float* out = (float*)d_out;
  unsigned int* flags = (unsigned int*)d_ws;        // 64KB: xcd/rendezvous words
  unsigned int* hbuf  = (unsigned int*)d_out;       // tagged exchange lives in d_out

  zero_ws<<<dim3(1056), dim3(512), 0, stream>>>(flags, hbuf);
  lstm_k<<<dim3(256), dim3(256), 0, stream>>>(obs, Wemb, Bemb, Wih, Whh, bih, bhh,
                                              out, flags, hbuf);
}